// Round 16
// baseline (179.252 us; speedup 1.0000x reference)
//
#include <hip/hip_runtime.h>
#include <math.h>

#define S_LEN 2048
#define DIM   512
#define M_TOT 8192
#define NCH   (S_LEN / 64)

typedef __attribute__((ext_vector_type(8))) short bf16x8;
typedef __attribute__((ext_vector_type(4))) short bf16x4;
typedef __attribute__((ext_vector_type(4))) float f32x4;
typedef __attribute__((ext_vector_type(16))) float f32x16;

#define MFMA(a, b, c)   __builtin_amdgcn_mfma_f32_16x16x32_bf16((a), (b), (c), 0, 0, 0)
#define MFMA32(a, b, c) __builtin_amdgcn_mfma_f32_32x32x16_bf16((a), (b), (c), 0, 0, 0)

// log2(e)/8 : baked into Wq so attention scores arrive as log2(e)*s/8,
// letting softmax use exp2 directly (exp(relu(s)/8) == exp2(relu(s'))).
#define QSCALE 0.18033688011112042f

__device__ __forceinline__ short f2b(float x) {
    union { float f; unsigned u; } v; v.f = x;
    unsigned r = v.u + 0x7FFFu + ((v.u >> 16) & 1u);   // RNE
    return (short)(r >> 16);
}

// packed f32x2 -> bf16x2 (RNE), single VOP3; low half = first arg
// (order verified by the passing proj_gemm staging path).
__device__ __forceinline__ unsigned cvtpk(float a, float b) {
    unsigned r;
    asm("v_cvt_pk_bf16_f32 %0, %1, %2" : "=v"(r) : "v"(a), "v"(b));
    return r;
}

__device__ __forceinline__ bf16x8 cvt8(float4 lo, float4 hi) {
    union { unsigned u[4]; bf16x8 v; } o;
    o.u[0] = cvtpk(lo.x, lo.y);
    o.u[1] = cvtpk(lo.z, lo.w);
    o.u[2] = cvtpk(hi.x, hi.y);
    o.u[3] = cvtpk(hi.z, hi.w);
    return o.v;
}

__device__ __forceinline__ float fast_exp2(float x) {
#if __has_builtin(__builtin_amdgcn_exp2f)
    return __builtin_amdgcn_exp2f(x);
#else
    return __expf(x * 0.693147180559945f);   // exp(x*ln2) == 2^x
#endif
}

// ---------------------------------------------------------------------------
// Wt[n][k] bf16 = transpose+convert of W[k][n] f32. 64x64 tiles.
// Wq additionally scaled by QSCALE (see above). UNCHANGED control.
// ---------------------------------------------------------------------------
__global__ __launch_bounds__(256) void prep_wt(const float* Wq, const float* Wk, const float* Wo,
                                               short* Wtq, short* Wtk, short* Wto) {
    const int zi = blockIdx.z;
    const float* W = zi == 0 ? Wq : zi == 1 ? Wk : Wo;
    short*      Wt = zi == 0 ? Wtq : zi == 1 ? Wtk : Wto;
    const float sc = zi == 0 ? QSCALE : 1.0f;
    __shared__ short Ts[64 * 72];
    const int t = threadIdx.x;
    const int k0 = blockIdx.x * 64, n0 = blockIdx.y * 64;
    #pragma unroll
    for (int it = 0; it < 4; ++it) {
        const int r = (t >> 4) + 16 * it;
        const int cq = t & 15;
        float4 v = *(const float4*)&W[(size_t)(k0 + r) * DIM + n0 + cq * 4];
        Ts[(4 * cq + 0) * 72 + r] = f2b(v.x * sc);
        Ts[(4 * cq + 1) * 72 + r] = f2b(v.y * sc);
        Ts[(4 * cq + 2) * 72 + r] = f2b(v.z * sc);
        Ts[(4 * cq + 3) * 72 + r] = f2b(v.w * sc);
    }
    __syncthreads();
    #pragma unroll
    for (int it = 0; it < 2; ++it) {
        const int n = (t >> 3) + 32 * it;
        const int sg = t & 7;
        *(bf16x8*)&Wt[(size_t)(n0 + n) * DIM + k0 + sg * 8] = *(const bf16x8*)&Ts[n * 72 + sg * 8];
    }
}

// ---------------------------------------------------------------------------
// Projection GEMMs v7 (fused 3): 512 threads / 8 waves, 128x128/BK=32,
// rotating single-barrier dbuf. UNCHANGED control (r15, passing).
// ---------------------------------------------------------------------------
__global__ __launch_bounds__(512) void proj_gemm(const float* __restrict__ X,
                                                 const float* __restrict__ Y,
                                                 const float* __restrict__ Z,
                                                 const short* __restrict__ Wtq,
                                                 const short* __restrict__ Wtk,
                                                 const short* __restrict__ Wto,
                                                 short* __restrict__ Qb,
                                                 short* __restrict__ Kb,
                                                 short* __restrict__ Vt) {
    const int zi = blockIdx.z;
    const float* A  = zi == 0 ? X : zi == 1 ? Y : Z;
    const short* Bw = zi == 0 ? Wtq : zi == 1 ? Wtk : Wto;

    __shared__ short As[2][128 * 40];   // 20 KB
    __shared__ short Bs[2][128 * 40];   // 20 KB
    const int tid = threadIdx.x;                     // 0..511
    const int w = tid >> 6, ln = tid & 63, l15 = ln & 15, quad = ln >> 4;
    const int m0 = blockIdx.x * 128, n0 = blockIdx.y * 128;
    const int wm = (w & 1) * 64, wn = (w >> 1) * 32;  // 2x4 wave grid

    const int r0 = tid >> 2;          // 0..127 (one row per thread)
    const int sg = tid & 3;
    const float* ap = A  + (size_t)(m0 + r0) * DIM + sg * 8;
    const short* bp = Bw + (size_t)(n0 + r0) * DIM + sg * 8;

    float4 a0l, a0h;
    bf16x8 b0;

    // prologue: k=0 -> buf0; prefetch k=32 into regs
    a0l = *(const float4*)ap; a0h = *(const float4*)(ap + 4);
    b0 = *(const bf16x8*)bp;
    *(bf16x8*)&As[0][r0 * 40 + sg * 8] = cvt8(a0l, a0h);
    *(bf16x8*)&Bs[0][r0 * 40 + sg * 8] = b0;
    a0l = *(const float4*)(ap + 32); a0h = *(const float4*)(ap + 36);
    b0 = *(const bf16x8*)(bp + 32);
    __syncthreads();

    f32x4 acc[4][2] = {};

    for (int k0 = 0; k0 < DIM; k0 += 32) {
        const int cur = (k0 >> 5) & 1;
        if (k0 + 32 < DIM) {    // stage regs (chunk k0+32) into other buffer
            *(bf16x8*)&As[cur ^ 1][r0 * 40 + sg * 8] = cvt8(a0l, a0h);
            *(bf16x8*)&Bs[cur ^ 1][r0 * 40 + sg * 8] = b0;
        }
        if (k0 + 64 < DIM) {    // prefetch chunk k0+64 into regs
            const int kn = k0 + 64;
            a0l = *(const float4*)(ap + kn); a0h = *(const float4*)(ap + kn + 4);
            b0 = *(const bf16x8*)(bp + kn);
        }

        bf16x8 af[4], bf[2];
        #pragma unroll
        for (int mf = 0; mf < 4; ++mf) af[mf] = *(const bf16x8*)&As[cur][(wm + 16 * mf + l15) * 40 + quad * 8];
        #pragma unroll
        for (int nf = 0; nf < 2; ++nf) bf[nf] = *(const bf16x8*)&Bs[cur][(wn + 16 * nf + l15) * 40 + quad * 8];
        #pragma unroll
        for (int mf = 0; mf < 4; ++mf)
            #pragma unroll
            for (int nf = 0; nf < 2; ++nf)
                acc[mf][nf] = MFMA(af[mf], bf[nf], acc[mf][nf]);
        __syncthreads();
    }

    if (zi < 2) {
        short* C = zi == 0 ? Qb : Kb;
        #pragma unroll
        for (int mf = 0; mf < 4; ++mf)
            #pragma unroll
            for (int nf = 0; nf < 2; ++nf)
                #pragma unroll
                for (int r = 0; r < 4; ++r)
                    C[(size_t)(m0 + wm + 16 * mf + 4 * quad + r) * DIM + n0 + wn + 16 * nf + l15] =
                        f2b(acc[mf][nf][r]);
    } else {
        #pragma unroll
        for (int mf = 0; mf < 4; ++mf)
            #pragma unroll
            for (int nf = 0; nf < 2; ++nf) {
                const int col = n0 + wn + 16 * nf + l15;
                const int h = col >> 6, hd = col & 63;
                const int row0_ = m0 + wm + 16 * mf + 4 * quad;
                const int bb = row0_ >> 11, s0 = row0_ & 2047;
                bf16x4 o = { f2b(acc[mf][nf][0]), f2b(acc[mf][nf][1]),
                             f2b(acc[mf][nf][2]), f2b(acc[mf][nf][3]) };
                *(bf16x4*)&Vt[((size_t)((bb * 8 + h) * 64 + hd)) * S_LEN + s0] = o;
            }
    }
}

// ---------------------------------------------------------------------------
// Final GEMM v4: attn-v8 recipe — 64m x 128n tile, 512 threads / 8 waves
// (2x4 wave grid, each wave 32x32, acc[2][2]); per-thread staging 1x bf16x4
// (A) + 1x bf16x8 (B) per k-step (was 2x bf16x8). Grid 512 blocks =
// 2 blocks/CU x 8 waves = 16 waves/CU (unchanged). Accumulation k-order per
// output element identical to v3 -> bit-identical numerics.
// XCD swizzle: each 64-row Ob panel's 4 n-tiles consecutive on one XCD.
// ---------------------------------------------------------------------------
__global__ __launch_bounds__(512) void out_gemm(const short* __restrict__ Ob,
                                                const short* __restrict__ Wto,
                                                float* __restrict__ Cout) {
    __shared__ short As[2][64 * 40];    //  10 KB
    __shared__ short Bs[2][128 * 40];   //  20 KB
    const int tid = threadIdx.x;                     // 0..511
    const int w = tid >> 6, ln = tid & 63, l15 = ln & 15, quad = ln >> 4;

    const int f = blockIdx.x;            // 512 blocks
    const int xcd = f & 7, j = f >> 3;   // j 0..63
    const int m0 = ((xcd << 4) + (j >> 2)) * 64;   // bijective: 128 m-strips
    const int n0 = (j & 3) * 128;
    const int wm = (w & 1) * 32, wn = (w >> 1) * 32;   // 2x4 wave grid

    // A staging: 8 threads/row (bf16x4 each); B staging: 4 threads/row (bf16x8)
    const int ar = tid >> 3, asg = tid & 7;
    const int br = tid >> 2, bsg = tid & 3;
    const short* ap = Ob  + (size_t)(m0 + ar) * DIM + asg * 4;
    const short* bp = Wto + (size_t)(n0 + br) * DIM + bsg * 8;

    bf16x4 a0;
    bf16x8 b0;

    // prologue: k=0 -> buf0; prefetch k=32 into regs
    a0 = *(const bf16x4*)ap;  b0 = *(const bf16x8*)bp;
    *(bf16x4*)&As[0][ar * 40 + asg * 4] = a0;
    *(bf16x8*)&Bs[0][br * 40 + bsg * 8] = b0;
    a0 = *(const bf16x4*)(ap + 32);  b0 = *(const bf16x8*)(bp + 32);
    __syncthreads();

    f32x4 acc[2][2] = {};

    for (int k0 = 0; k0 < DIM; k0 += 32) {
        const int cur = (k0 >> 5) & 1;
        if (k0 + 32 < DIM) {    // stage regs (chunk k0+32) into other buffer
            *(bf16x4*)&As[cur ^ 1][ar * 40 + asg * 4] = a0;
            *(bf16x8*)&Bs[cur ^ 1][br * 40 + bsg * 8] = b0;
        }
        if (k0 + 64 < DIM) {    // prefetch chunk k0+64 into regs
            a0 = *(const bf16x4*)(ap + k0 + 64);
            b0 = *(const bf16x8*)(bp + k0 + 64);
        }

        bf16x8 af[2], bf[2];
        #pragma unroll
        for (int mf = 0; mf < 2; ++mf) af[mf] = *(const bf16x8*)&As[cur][(wm + 16 * mf + l15) * 40 + quad * 8];
        #pragma unroll
        for (int nf = 0; nf < 2; ++nf) bf[nf] = *(const bf16x8*)&Bs[cur][(wn + 16 * nf + l15) * 40 + quad * 8];
        #pragma unroll
        for (int mf = 0; mf < 2; ++mf)
            #pragma unroll
            for (int nf = 0; nf < 2; ++nf)
                acc[mf][nf] = MFMA(af[mf], bf[nf], acc[mf][nf]);
        __syncthreads();
    }
    #pragma unroll
    for (int mf = 0; mf < 2; ++mf)
        #pragma unroll
        for (int nf = 0; nf < 2; ++nf)
            #pragma unroll
            for (int r = 0; r < 4; ++r)
                Cout[(size_t)(m0 + wm + 16 * mf + 4 * quad + r) * DIM + n0 + wn + 16 * nf + l15] =
                    acc[mf][nf][r];
}

// ---------------------------------------------------------------------------
// Attention v8 (PASSING, byte-identical control): 8 waves x 32q = 256q/block,
// 256 blocks. Per-wave compute identical to v6; K/V staging 8 threads/row.
// 32x32 MFMA + register-renamed P->V permutation. 0 bank conflicts.
// ---------------------------------------------------------------------------
__global__ __launch_bounds__(512) void attn_mfma(const short* __restrict__ Qb,
                                                 const short* __restrict__ Kb,
                                                 const short* __restrict__ Vtg,
                                                 short* __restrict__ Ob) {
    __shared__ short Ks[2][64 * 72];   // [key][d]
    __shared__ short Vs[2][64 * 72];   // [hd][perm-col]  (from pre-transposed Vt)
    __shared__ float Ds[8][32];

    const int tid = threadIdx.x;
    const int w = tid >> 6, ln = tid & 63, n31 = ln & 31, hL = ln >> 5;

    const int f = blockIdx.x;                     // 256 blocks
    const int swz = ((f & 7) << 5) | (f >> 3);    // bijective; 4 bh per XCD
    const int qt0 = (swz & 7) * 256;
    const int bh  = swz >> 3;
    const int b = bh >> 3, h = bh & 7;
    const size_t tokbase = (size_t)b * S_LEN;

    // Q as B-operand, resident: wave w covers q rows [qt0+32w, +32)
    const int q0w = qt0 + 32 * w;
    bf16x8 qf[4];
    #pragma unroll
    for (int dk = 0; dk < 4; ++dk)
        qf[dk] = *(const bf16x8*)&Qb[(tokbase + q0w + n31) * DIM + h * 64 + 16 * dk + 8 * hL];

    // staging: 8 threads per row. K: one bf16x8 (8 shorts) per thread.
    // V: one bf16x8 load, two bf16x4 writes (column permutation).
    const int srow = tid >> 3, sg = tid & 7;      // srow 0..63, sg 0..7
    const int vm = sg & 3, vhalf = sg >> 2;
    const short* kbase = Kb  + (tokbase + srow) * DIM + h * 64 + sg * 8;
    const short* vbase = Vtg + ((size_t)bh * 64 + srow) * S_LEN + 32 * vhalf + 8 * vm;
    const int kw_off = srow * 72 + sg * 8;
    const int vw_off = srow * 72 + 16 * vm + 4 * vhalf;

    union b8split { bf16x8 v; struct { bf16x4 lo, hi; } s; };

    bf16x8 kr;
    b8split vr;

    f32x16 oacc[2] = {};
    f32x4 d4 = {0.f, 0.f, 0.f, 0.f};

    // prologue: chunk0 -> buf0; prefetch chunk1 regs
    kr   = *(const bf16x8*)kbase;
    vr.v = *(const bf16x8*)vbase;
    *(bf16x8*)&Ks[0][kw_off] = kr;
    *(bf16x4*)&Vs[0][vw_off]     = vr.s.lo;
    *(bf16x4*)&Vs[0][vw_off + 8] = vr.s.hi;
    kr   = *(const bf16x8*)(kbase + (size_t)64 * DIM);
    vr.v = *(const bf16x8*)(vbase + 64);
    __syncthreads();

    for (int kc = 0; kc < NCH; ++kc) {
        const int cur = kc & 1;
        if (kc + 1 < NCH) {     // stage chunk kc+1 (regs) into other buffer
            *(bf16x8*)&Ks[cur ^ 1][kw_off] = kr;
            *(bf16x4*)&Vs[cur ^ 1][vw_off]     = vr.s.lo;
            *(bf16x4*)&Vs[cur ^ 1][vw_off + 8] = vr.s.hi;
        }
        if (kc + 2 < NCH) {     // prefetch chunk kc+2 into regs (L2-resident)
            kr   = *(const bf16x8*)(kbase + (size_t)(kc + 2) * 64 * DIM);
            vr.v = *(const bf16x8*)(vbase + (size_t)(kc + 2) * 64);
        }

        // ---- phase 1: S^T[key][q] = K * Q^T (2 key-tiles of 32 x 32 q) ----
        f32x16 sacc[2] = {};
        __builtin_amdgcn_s_setprio(1);
        #pragma unroll
        for (int kt = 0; kt < 2; ++kt)
            #pragma unroll
            for (int dk = 0; dk < 4; ++dk) {
                bf16x8 ka = *(const bf16x8*)&Ks[cur][(32 * kt + n31) * 72 + 16 * dk + 8 * hL];
                sacc[kt] = MFMA32(ka, qf[dk], sacc[kt]);
            }
        __builtin_amdgcn_s_setprio(0);

        // ---- e = exp2(max(s,0)), pack to bf16 pairs (lane-local, q = n31).
        // cp[8kt+p] = keys 32kt + 4hL + {0,1|2,3|8,9|10,11|16,...} per p. ----
        unsigned cp[16];
        #pragma unroll
        for (int kt = 0; kt < 2; ++kt)
            #pragma unroll
            for (int p = 0; p < 8; ++p) {
                const float e0 = fast_exp2(fmaxf(sacc[kt][2 * p], 0.f));
                const float e1 = fast_exp2(fmaxf(sacc[kt][2 * p + 1], 0.f));
                d4[p & 3] += e0 + e1;
                cp[8 * kt + p] = cvtpk(e0, e1);
            }

        // ---- phase 2: O[q][hd] += P * V, 4 MFMAs over key-subsets.
        // pf[m] = pure register renaming of the lane's own C/D words. ----
        __builtin_amdgcn_s_setprio(1);
        #pragma unroll
        for (int m = 0; m < 4; ++m) {
            union { unsigned u[4]; bf16x8 v; } pu;
            pu.u[0] = cp[2 * m];     pu.u[1] = cp[2 * m + 1];
            pu.u[2] = cp[2 * m + 8]; pu.u[3] = cp[2 * m + 9];
            #pragma unroll
            for (int nt = 0; nt < 2; ++nt) {
                bf16x8 vb = *(const bf16x8*)&Vs[cur][(32 * nt + n31) * 72 + 16 * m + 8 * hL];
                oacc[nt] = MFMA32(pu.v, vb, oacc[nt]);
            }
        }
        __builtin_amdgcn_s_setprio(0);
        __syncthreads();   // staged writes visible; readers done before overwrite
    }

    // ---- denominator: lane-local partials + one half-exchange ----
    float dtot = (d4[0] + d4[1]) + (d4[2] + d4[3]);
    dtot += __shfl_xor(dtot, 32);
    const float dinv = 1.0f / dtot;
    if (ln < 32) Ds[w][n31] = dinv;
    __syncthreads();
    f32x4 dv[4];
    #pragma unroll
    for (int g = 0; g < 4; ++g)
        dv[g] = *(const f32x4*)&Ds[w][8 * g + 4 * hL];

    // ---- normalize + store bf16 ----
    #pragma unroll
    for (int nt = 0; nt < 2; ++nt)
        #pragma unroll
        for (int r = 0; r < 16; ++r) {
            const int qb = 32 * w + 4 * hL + 8 * (r >> 2) + (r & 3);
            Ob[(tokbase + qt0 + qb) * DIM + h * 64 + 32 * nt + n31] =
                f2b(oacc[nt][r] * dv[r >> 2][r & 3]);
        }
}

// ---------------------------------------------------------------------------
extern "C" void kernel_launch(void* const* d_in, const int* in_sizes, int n_in,
                              void* d_out, int out_size, void* d_ws, size_t ws_size,
                              hipStream_t stream) {
    const float* X  = (const float*)d_in[0];
    const float* Y  = (const float*)d_in[1];
    const float* Z  = (const float*)d_in[2];
    const float* Wq = (const float*)d_in[3];
    const float* Wk = (const float*)d_in[4];
    // d_in[5] = Wv dead in reference forward
    const float* Wo = (const float*)d_in[6];

    char* p = (char*)d_ws;
    const size_t MD = (size_t)M_TOT * DIM;
    short* Qb  = (short*)p; p += MD * 2;
    short* Kb  = (short*)p; p += MD * 2;
    short* Vt  = (short*)p; p += MD * 2;
    short* Ob  = (short*)p; p += MD * 2;
    short* Wtq = (short*)p; p += (size_t)DIM * DIM * 2;
    short* Wtk = (short*)p; p += (size_t)DIM * DIM * 2;
    short* Wto = (short*)p; p += (size_t)DIM * DIM * 2;

    prep_wt<<<dim3(8, 8, 3), 256, 0, stream>>>(Wq, Wk, Wo, Wtq, Wtk, Wto);
    proj_gemm<<<dim3(64, 4, 3), 512, 0, stream>>>(X, Y, Z, Wtq, Wtk, Wto, Qb, Kb, Vt);
    attn_mfma<<<dim3(256), 512, 0, stream>>>(Qb, Kb, Vt, Ob);
    out_gemm<<<dim3(512), 512, 0, stream>>>(Ob, Wto, (float*)d_out);
}

// Round 20
// 176.345 us; speedup vs baseline: 1.0165x; 1.0165x over previous
//
#include <hip/hip_runtime.h>
#include <math.h>

#define S_LEN 2048
#define DIM   512
#define M_TOT 8192
#define NCH   (S_LEN / 64)

typedef __attribute__((ext_vector_type(8))) short bf16x8;
typedef __attribute__((ext_vector_type(4))) short bf16x4;
typedef __attribute__((ext_vector_type(4))) float f32x4;
typedef __attribute__((ext_vector_type(16))) float f32x16;

#define MFMA(a, b, c)   __builtin_amdgcn_mfma_f32_16x16x32_bf16((a), (b), (c), 0, 0, 0)
#define MFMA32(a, b, c) __builtin_amdgcn_mfma_f32_32x32x16_bf16((a), (b), (c), 0, 0, 0)

// log2(e)/8 : baked into Wq so attention scores arrive as log2(e)*s/8,
// letting softmax use exp2 directly (exp(relu(s)/8) == exp2(relu(s'))).
#define QSCALE 0.18033688011112042f

__device__ __forceinline__ short f2b(float x) {
    union { float f; unsigned u; } v; v.f = x;
    unsigned r = v.u + 0x7FFFu + ((v.u >> 16) & 1u);   // RNE
    return (short)(r >> 16);
}

// packed f32x2 -> bf16x2 (RNE), single VOP3; low half = first arg
// (order verified by the passing proj_gemm staging path).
__device__ __forceinline__ unsigned cvtpk(float a, float b) {
    unsigned r;
    asm("v_cvt_pk_bf16_f32 %0, %1, %2" : "=v"(r) : "v"(a), "v"(b));
    return r;
}

__device__ __forceinline__ bf16x8 cvt8(float4 lo, float4 hi) {
    union { unsigned u[4]; bf16x8 v; } o;
    o.u[0] = cvtpk(lo.x, lo.y);
    o.u[1] = cvtpk(lo.z, lo.w);
    o.u[2] = cvtpk(hi.x, hi.y);
    o.u[3] = cvtpk(hi.z, hi.w);
    return o.v;
}

__device__ __forceinline__ float fast_exp2(float x) {
#if __has_builtin(__builtin_amdgcn_exp2f)
    return __builtin_amdgcn_exp2f(x);
#else
    return __expf(x * 0.693147180559945f);   // exp(x*ln2) == 2^x
#endif
}

// ---------------------------------------------------------------------------
// Wt[n][k] bf16 = transpose+convert of W[k][n] f32. 64x64 tiles.
// Wq additionally scaled by QSCALE (see above).
// ---------------------------------------------------------------------------
__global__ __launch_bounds__(256) void prep_wt(const float* Wq, const float* Wk, const float* Wo,
                                               short* Wtq, short* Wtk, short* Wto) {
    const int zi = blockIdx.z;
    const float* W = zi == 0 ? Wq : zi == 1 ? Wk : Wo;
    short*      Wt = zi == 0 ? Wtq : zi == 1 ? Wtk : Wto;
    const float sc = zi == 0 ? QSCALE : 1.0f;
    __shared__ short Ts[64 * 72];
    const int t = threadIdx.x;
    const int k0 = blockIdx.x * 64, n0 = blockIdx.y * 64;
    #pragma unroll
    for (int it = 0; it < 4; ++it) {
        const int r = (t >> 4) + 16 * it;
        const int cq = t & 15;
        float4 v = *(const float4*)&W[(size_t)(k0 + r) * DIM + n0 + cq * 4];
        Ts[(4 * cq + 0) * 72 + r] = f2b(v.x * sc);
        Ts[(4 * cq + 1) * 72 + r] = f2b(v.y * sc);
        Ts[(4 * cq + 2) * 72 + r] = f2b(v.z * sc);
        Ts[(4 * cq + 3) * 72 + r] = f2b(v.w * sc);
    }
    __syncthreads();
    #pragma unroll
    for (int it = 0; it < 2; ++it) {
        const int n = (t >> 3) + 32 * it;
        const int sg = t & 7;
        *(bf16x8*)&Wt[(size_t)(n0 + n) * DIM + k0 + sg * 8] = *(const bf16x8*)&Ts[n * 72 + sg * 8];
    }
}

// ---------------------------------------------------------------------------
// Projection GEMMs v7 (fused 3): 512 threads / 8 waves, 128x128/BK=32,
// rotating single-barrier dbuf. (r15 passing version, byte-identical.)
// ---------------------------------------------------------------------------
__global__ __launch_bounds__(512) void proj_gemm(const float* __restrict__ X,
                                                 const float* __restrict__ Y,
                                                 const float* __restrict__ Z,
                                                 const short* __restrict__ Wtq,
                                                 const short* __restrict__ Wtk,
                                                 const short* __restrict__ Wto,
                                                 short* __restrict__ Qb,
                                                 short* __restrict__ Kb,
                                                 short* __restrict__ Vt) {
    const int zi = blockIdx.z;
    const float* A  = zi == 0 ? X : zi == 1 ? Y : Z;
    const short* Bw = zi == 0 ? Wtq : zi == 1 ? Wtk : Wto;

    __shared__ short As[2][128 * 40];   // 20 KB
    __shared__ short Bs[2][128 * 40];   // 20 KB
    const int tid = threadIdx.x;                     // 0..511
    const int w = tid >> 6, ln = tid & 63, l15 = ln & 15, quad = ln >> 4;
    const int m0 = blockIdx.x * 128, n0 = blockIdx.y * 128;
    const int wm = (w & 1) * 64, wn = (w >> 1) * 32;  // 2x4 wave grid

    const int r0 = tid >> 2;          // 0..127 (one row per thread)
    const int sg = tid & 3;
    const float* ap = A  + (size_t)(m0 + r0) * DIM + sg * 8;
    const short* bp = Bw + (size_t)(n0 + r0) * DIM + sg * 8;

    float4 a0l, a0h;
    bf16x8 b0;

    // prologue: k=0 -> buf0; prefetch k=32 into regs
    a0l = *(const float4*)ap; a0h = *(const float4*)(ap + 4);
    b0 = *(const bf16x8*)bp;
    *(bf16x8*)&As[0][r0 * 40 + sg * 8] = cvt8(a0l, a0h);
    *(bf16x8*)&Bs[0][r0 * 40 + sg * 8] = b0;
    a0l = *(const float4*)(ap + 32); a0h = *(const float4*)(ap + 36);
    b0 = *(const bf16x8*)(bp + 32);
    __syncthreads();

    f32x4 acc[4][2] = {};

    for (int k0 = 0; k0 < DIM; k0 += 32) {
        const int cur = (k0 >> 5) & 1;
        if (k0 + 32 < DIM) {    // stage regs (chunk k0+32) into other buffer
            *(bf16x8*)&As[cur ^ 1][r0 * 40 + sg * 8] = cvt8(a0l, a0h);
            *(bf16x8*)&Bs[cur ^ 1][r0 * 40 + sg * 8] = b0;
        }
        if (k0 + 64 < DIM) {    // prefetch chunk k0+64 into regs
            const int kn = k0 + 64;
            a0l = *(const float4*)(ap + kn); a0h = *(const float4*)(ap + kn + 4);
            b0 = *(const bf16x8*)(bp + kn);
        }

        bf16x8 af[4], bf[2];
        #pragma unroll
        for (int mf = 0; mf < 4; ++mf) af[mf] = *(const bf16x8*)&As[cur][(wm + 16 * mf + l15) * 40 + quad * 8];
        #pragma unroll
        for (int nf = 0; nf < 2; ++nf) bf[nf] = *(const bf16x8*)&Bs[cur][(wn + 16 * nf + l15) * 40 + quad * 8];
        #pragma unroll
        for (int mf = 0; mf < 4; ++mf)
            #pragma unroll
            for (int nf = 0; nf < 2; ++nf)
                acc[mf][nf] = MFMA(af[mf], bf[nf], acc[mf][nf]);
        __syncthreads();
    }

    if (zi < 2) {
        short* C = zi == 0 ? Qb : Kb;
        #pragma unroll
        for (int mf = 0; mf < 4; ++mf)
            #pragma unroll
            for (int nf = 0; nf < 2; ++nf)
                #pragma unroll
                for (int r = 0; r < 4; ++r)
                    C[(size_t)(m0 + wm + 16 * mf + 4 * quad + r) * DIM + n0 + wn + 16 * nf + l15] =
                        f2b(acc[mf][nf][r]);
    } else {
        #pragma unroll
        for (int mf = 0; mf < 4; ++mf)
            #pragma unroll
            for (int nf = 0; nf < 2; ++nf) {
                const int col = n0 + wn + 16 * nf + l15;
                const int h = col >> 6, hd = col & 63;
                const int row0_ = m0 + wm + 16 * mf + 4 * quad;
                const int bb = row0_ >> 11, s0 = row0_ & 2047;
                bf16x4 o = { f2b(acc[mf][nf][0]), f2b(acc[mf][nf][1]),
                             f2b(acc[mf][nf][2]), f2b(acc[mf][nf][3]) };
                *(bf16x4*)&Vt[((size_t)((bb * 8 + h) * 64 + hd)) * S_LEN + s0] = o;
            }
    }
}

// ---------------------------------------------------------------------------
// Final GEMM v3: r2's proven 64x64/BK=32 indexing + rotating single-barrier
// double-buffer (r15 passing version, byte-identical).
// ---------------------------------------------------------------------------
__global__ __launch_bounds__(256) void out_gemm(const short* __restrict__ Ob,
                                                const short* __restrict__ Wto,
                                                float* __restrict__ Cout) {
    __shared__ short As[2][64 * 40];   // 10 KB
    __shared__ short Bs[2][64 * 40];   // 10 KB
    const int tid = threadIdx.x;
    const int w = tid >> 6, ln = tid & 63, l15 = ln & 15, quad = ln >> 4;

    const int f = blockIdx.x;
    const int swz = ((f & 7) << 7) | (f >> 3);      // bijective, 1024 blocks
    const int m0 = (swz >> 3) * 64, n0 = (swz & 7) * 64;
    const int wm = (w & 1) * 32, wn = (w >> 1) * 32;

    const int row = tid >> 2;         // 0..63
    const int sg = tid & 3;           // k sub-offset
    const short* ap = Ob  + (size_t)(m0 + row) * DIM + sg * 8;
    const short* bp = Wto + (size_t)(n0 + row) * DIM + sg * 8;

    bf16x8 a0, b0;

    // prologue: k=0 -> buf0; prefetch k=32 into regs
    a0 = *(const bf16x8*)ap;  b0 = *(const bf16x8*)bp;
    *(bf16x8*)&As[0][row * 40 + sg * 8] = a0;
    *(bf16x8*)&Bs[0][row * 40 + sg * 8] = b0;
    a0 = *(const bf16x8*)(ap + 32);  b0 = *(const bf16x8*)(bp + 32);
    __syncthreads();

    f32x4 acc[2][2] = {};

    for (int k0 = 0; k0 < DIM; k0 += 32) {
        const int cur = (k0 >> 5) & 1;
        if (k0 + 32 < DIM) {    // stage regs (chunk k0+32) into other buffer
            *(bf16x8*)&As[cur ^ 1][row * 40 + sg * 8] = a0;
            *(bf16x8*)&Bs[cur ^ 1][row * 40 + sg * 8] = b0;
        }
        if (k0 + 64 < DIM) {    // prefetch chunk k0+64 into regs
            a0 = *(const bf16x8*)(ap + k0 + 64);
            b0 = *(const bf16x8*)(bp + k0 + 64);
        }

        bf16x8 af[2], bf[2];
        #pragma unroll
        for (int mf = 0; mf < 2; ++mf) af[mf] = *(const bf16x8*)&As[cur][(wm + 16 * mf + l15) * 40 + quad * 8];
        #pragma unroll
        for (int nf = 0; nf < 2; ++nf) bf[nf] = *(const bf16x8*)&Bs[cur][(wn + 16 * nf + l15) * 40 + quad * 8];
        #pragma unroll
        for (int mf = 0; mf < 2; ++mf)
            #pragma unroll
            for (int nf = 0; nf < 2; ++nf)
                acc[mf][nf] = MFMA(af[mf], bf[nf], acc[mf][nf]);
        __syncthreads();
    }
    #pragma unroll
    for (int mf = 0; mf < 2; ++mf)
        #pragma unroll
        for (int nf = 0; nf < 2; ++nf)
            #pragma unroll
            for (int r = 0; r < 4; ++r)
                Cout[(size_t)(m0 + wm + 16 * mf + 4 * quad + r) * DIM + n0 + wn + 16 * nf + l15] =
                    acc[mf][nf][r];
}

// ---------------------------------------------------------------------------
// Attention v8 (PASSING, byte-identical r15 version): 8 waves x 32q =
// 256q/block, 256 blocks. Per-wave compute identical to v6; K/V staging
// 8 threads/row. 32x32 MFMA + register-renamed P->V permutation.
// 0 bank conflicts.
// ---------------------------------------------------------------------------
__global__ __launch_bounds__(512) void attn_mfma(const short* __restrict__ Qb,
                                                 const short* __restrict__ Kb,
                                                 const short* __restrict__ Vtg,
                                                 short* __restrict__ Ob) {
    __shared__ short Ks[2][64 * 72];   // [key][d]
    __shared__ short Vs[2][64 * 72];   // [hd][perm-col]  (from pre-transposed Vt)
    __shared__ float Ds[8][32];

    const int tid = threadIdx.x;
    const int w = tid >> 6, ln = tid & 63, n31 = ln & 31, hL = ln >> 5;

    const int f = blockIdx.x;                     // 256 blocks
    const int swz = ((f & 7) << 5) | (f >> 3);    // bijective; 4 bh per XCD
    const int qt0 = (swz & 7) * 256;
    const int bh  = swz >> 3;
    const int b = bh >> 3, h = bh & 7;
    const size_t tokbase = (size_t)b * S_LEN;

    // Q as B-operand, resident: wave w covers q rows [qt0+32w, +32)
    const int q0w = qt0 + 32 * w;
    bf16x8 qf[4];
    #pragma unroll
    for (int dk = 0; dk < 4; ++dk)
        qf[dk] = *(const bf16x8*)&Qb[(tokbase + q0w + n31) * DIM + h * 64 + 16 * dk + 8 * hL];

    // staging: 8 threads per row. K: one bf16x8 (8 shorts) per thread.
    // V: one bf16x8 load, two bf16x4 writes (column permutation).
    const int srow = tid >> 3, sg = tid & 7;      // srow 0..63, sg 0..7
    const int vm = sg & 3, vhalf = sg >> 2;
    const short* kbase = Kb  + (tokbase + srow) * DIM + h * 64 + sg * 8;
    const short* vbase = Vtg + ((size_t)bh * 64 + srow) * S_LEN + 32 * vhalf + 8 * vm;
    const int kw_off = srow * 72 + sg * 8;
    const int vw_off = srow * 72 + 16 * vm + 4 * vhalf;

    union b8split { bf16x8 v; struct { bf16x4 lo, hi; } s; };

    bf16x8 kr;
    b8split vr;

    f32x16 oacc[2] = {};
    f32x4 d4 = {0.f, 0.f, 0.f, 0.f};

    // prologue: chunk0 -> buf0; prefetch chunk1 regs
    kr   = *(const bf16x8*)kbase;
    vr.v = *(const bf16x8*)vbase;
    *(bf16x8*)&Ks[0][kw_off] = kr;
    *(bf16x4*)&Vs[0][vw_off]     = vr.s.lo;
    *(bf16x4*)&Vs[0][vw_off + 8] = vr.s.hi;
    kr   = *(const bf16x8*)(kbase + (size_t)64 * DIM);
    vr.v = *(const bf16x8*)(vbase + 64);
    __syncthreads();

    for (int kc = 0; kc < NCH; ++kc) {
        const int cur = kc & 1;
        if (kc + 1 < NCH) {     // stage chunk kc+1 (regs) into other buffer
            *(bf16x8*)&Ks[cur ^ 1][kw_off] = kr;
            *(bf16x4*)&Vs[cur ^ 1][vw_off]     = vr.s.lo;
            *(bf16x4*)&Vs[cur ^ 1][vw_off + 8] = vr.s.hi;
        }
        if (kc + 2 < NCH) {     // prefetch chunk kc+2 into regs (L2-resident)
            kr   = *(const bf16x8*)(kbase + (size_t)(kc + 2) * 64 * DIM);
            vr.v = *(const bf16x8*)(vbase + (size_t)(kc + 2) * 64);
        }

        // ---- phase 1: S^T[key][q] = K * Q^T (2 key-tiles of 32 x 32 q) ----
        f32x16 sacc[2] = {};
        __builtin_amdgcn_s_setprio(1);
        #pragma unroll
        for (int kt = 0; kt < 2; ++kt)
            #pragma unroll
            for (int dk = 0; dk < 4; ++dk) {
                bf16x8 ka = *(const bf16x8*)&Ks[cur][(32 * kt + n31) * 72 + 16 * dk + 8 * hL];
                sacc[kt] = MFMA32(ka, qf[dk], sacc[kt]);
            }
        __builtin_amdgcn_s_setprio(0);

        // ---- e = exp2(max(s,0)), pack to bf16 pairs (lane-local, q = n31).
        // cp[8kt+p] = keys 32kt + 4hL + {0,1|2,3|8,9|10,11|16,...} per p. ----
        unsigned cp[16];
        #pragma unroll
        for (int kt = 0; kt < 2; ++kt)
            #pragma unroll
            for (int p = 0; p < 8; ++p) {
                const float e0 = fast_exp2(fmaxf(sacc[kt][2 * p], 0.f));
                const float e1 = fast_exp2(fmaxf(sacc[kt][2 * p + 1], 0.f));
                d4[p & 3] += e0 + e1;
                cp[8 * kt + p] = cvtpk(e0, e1);
            }

        // ---- phase 2: O[q][hd] += P * V, 4 MFMAs over key-subsets.
        // pf[m] = pure register renaming of the lane's own C/D words. ----
        __builtin_amdgcn_s_setprio(1);
        #pragma unroll
        for (int m = 0; m < 4; ++m) {
            union { unsigned u[4]; bf16x8 v; } pu;
            pu.u[0] = cp[2 * m];     pu.u[1] = cp[2 * m + 1];
            pu.u[2] = cp[2 * m + 8]; pu.u[3] = cp[2 * m + 9];
            #pragma unroll
            for (int nt = 0; nt < 2; ++nt) {
                bf16x8 vb = *(const bf16x8*)&Vs[cur][(32 * nt + n31) * 72 + 16 * m + 8 * hL];
                oacc[nt] = MFMA32(pu.v, vb, oacc[nt]);
            }
        }
        __builtin_amdgcn_s_setprio(0);
        __syncthreads();   // staged writes visible; readers done before overwrite
    }

    // ---- denominator: lane-local partials + one half-exchange ----
    float dtot = (d4[0] + d4[1]) + (d4[2] + d4[3]);
    dtot += __shfl_xor(dtot, 32);
    const float dinv = 1.0f / dtot;
    if (ln < 32) Ds[w][n31] = dinv;
    __syncthreads();
    f32x4 dv[4];
    #pragma unroll
    for (int g = 0; g < 4; ++g)
        dv[g] = *(const f32x4*)&Ds[w][8 * g + 4 * hL];

    // ---- normalize + store bf16 ----
    #pragma unroll
    for (int nt = 0; nt < 2; ++nt)
        #pragma unroll
        for (int r = 0; r < 16; ++r) {
            const int qb = 32 * w + 4 * hL + 8 * (r >> 2) + (r & 3);
            Ob[(tokbase + qt0 + qb) * DIM + h * 64 + 32 * nt + n31] =
                f2b(oacc[nt][r] * dv[r >> 2][r & 3]);
        }
}

// ---------------------------------------------------------------------------
extern "C" void kernel_launch(void* const* d_in, const int* in_sizes, int n_in,
                              void* d_out, int out_size, void* d_ws, size_t ws_size,
                              hipStream_t stream) {
    const float* X  = (const float*)d_in[0];
    const float* Y  = (const float*)d_in[1];
    const float* Z  = (const float*)d_in[2];
    const float* Wq = (const float*)d_in[3];
    const float* Wk = (const float*)d_in[4];
    // d_in[5] = Wv dead in reference forward
    const float* Wo = (const float*)d_in[6];

    char* p = (char*)d_ws;
    const size_t MD = (size_t)M_TOT * DIM;
    short* Qb  = (short*)p; p += MD * 2;
    short* Kb  = (short*)p; p += MD * 2;
    short* Vt  = (short*)p; p += MD * 2;
    short* Ob  = (short*)p; p += MD * 2;
    short* Wtq = (short*)p; p += (size_t)DIM * DIM * 2;
    short* Wtk = (short*)p; p += (size_t)DIM * DIM * 2;
    short* Wto = (short*)p; p += (size_t)DIM * DIM * 2;

    prep_wt<<<dim3(8, 8, 3), 256, 0, stream>>>(Wq, Wk, Wo, Wtq, Wtk, Wto);
    proj_gemm<<<dim3(64, 4, 3), 512, 0, stream>>>(X, Y, Z, Wtq, Wtk, Wto, Qb, Kb, Vt);
    attn_mfma<<<dim3(256), 512, 0, stream>>>(Qb, Kb, Vt, Ob);
    out_gemm<<<dim3(1024), 256, 0, stream>>>(Ob, Wto, (float*)d_out);
}